// Round 10
// baseline (232.241 us; speedup 1.0000x reference)
//
#include <hip/hip_runtime.h>
#include <hip/hip_fp16.h>
#include <math.h>

#define N_NODES   50000
#define N_EDGES   800000
#define IN_DIM    128
#define HID       64
#define OUT_DIM   128
#define N_GRAPHS  256
#define MAX_DEG   64      // ELL row stride; P(indeg>64) for Binomial(800k,1/50k) ~ 0
#define PARTS     8       // XCD count; blockIdx%8 -> XCD round-robin heuristic
#define PSIZE     (N_NODES / PARTS)
#define EPB       4096    // edges per build chunk (= 256 threads x 16 edges)
#define AGG_NPB   64      // nodes per agg block (4 waves x 16 quads, 4 lanes/node)
#define GEMM_BLKS 782     // ceil(50000/64)
#define PSTRIDE   ((size_t)N_NODES * 32)   // halves per feature plane

typedef _Float16 half8 __attribute__((ext_vector_type(8)));
typedef float floatx4 __attribute__((ext_vector_type(4)));

// ---------------- fused: layer-1 GEMM (UNSCALED x@W1, plane-split store) || edge build ----------------

__global__ __launch_bounds__(256) void k_fused1(const float* __restrict__ A,
                                                const float* __restrict__ W1,
                                                __half* __restrict__ C,
                                                const int* __restrict__ src,
                                                const int* __restrict__ dst,
                                                int* __restrict__ deg,
                                                int* __restrict__ col) {
    if (blockIdx.x < GEMM_BLKS) {
        constexpr int K = IN_DIM, S = K / 32;
        __shared__ __half wlds[IN_DIM * HID];   // packed B fragments, 16 KB

#pragma unroll
        for (int u = 0; u < 8; u++) {
            int o = threadIdx.x * 32 + u * 4;          // 8192 floats / 256 thr
            float4 w = *(const float4*)(W1 + o);
            int k = o >> 6, n = o & 63;
            int bi = (((k >> 3) * 64) + n) * 8 + (k & 7);
            wlds[bi]      = __float2half(w.x);
            wlds[bi + 8]  = __float2half(w.y);
            wlds[bi + 16] = __float2half(w.z);
            wlds[bi + 24] = __float2half(w.w);
        }
        __syncthreads();

        int wv   = threadIdx.x >> 6;
        int lane = threadIdx.x & 63;
        int quad = lane >> 4, l15 = lane & 15;
        int row0 = blockIdx.x * 64 + wv * 16;
        if (row0 >= N_NODES) return;   // after barrier: tail waves drop out

        half8 bf[S][4];
#pragma unroll
        for (int s = 0; s < S; s++)
#pragma unroll
            for (int j = 0; j < 4; j++)
                bf[s][j] = *(const half8*)&wlds[(((4 * s + quad) * 64) + 16 * j + l15) * 8];

        floatx4 acc[4];
#pragma unroll
        for (int j = 0; j < 4; j++) acc[j] = 0.f;

        int arow = row0 + l15;
#pragma unroll
        for (int s = 0; s < S; s++) {
            float4 xa = *(const float4*)(A + (size_t)arow * K + 32 * s + quad * 8);
            float4 xb = *(const float4*)(A + (size_t)arow * K + 32 * s + quad * 8 + 4);
            half8 af;
            af[0] = (_Float16)xa.x; af[1] = (_Float16)xa.y;
            af[2] = (_Float16)xa.z; af[3] = (_Float16)xa.w;
            af[4] = (_Float16)xb.x; af[5] = (_Float16)xb.y;
            af[6] = (_Float16)xb.z; af[7] = (_Float16)xb.w;
#pragma unroll
            for (int j = 0; j < 4; j++)
                acc[j] = __builtin_amdgcn_mfma_f32_16x16x32_f16(af, bf[s][j], acc[j], 0, 0, 0);
        }
#pragma unroll
        for (int j = 0; j < 4; j++)
#pragma unroll
            for (int r = 0; r < 4; r++)
                C[(size_t)(j >> 1) * PSTRIDE + (size_t)(row0 + quad * 4 + r) * 32 +
                  16 * (j & 1) + l15] = __float2half(acc[j][r]);
    } else {
        int bid   = blockIdx.x - GEMM_BLKS;
        int p     = bid & (PARTS - 1);
        int chunk = bid >> 3;
        int e0    = chunk * EPB + threadIdx.x * 16;
        if (e0 + 16 > N_EDGES) return;
        int lo = p * PSIZE, hi = lo + PSIZE;

        int dd[16], ss[16];
        const int4* d4 = (const int4*)(dst + e0);
        const int4* s4 = (const int4*)(src + e0);
#pragma unroll
        for (int j = 0; j < 4; j++) {
            int4 q = d4[j];
            dd[4 * j + 0] = q.x; dd[4 * j + 1] = q.y;
            dd[4 * j + 2] = q.z; dd[4 * j + 3] = q.w;
        }
#pragma unroll
        for (int j = 0; j < 4; j++) {
            int4 q = s4[j];
            ss[4 * j + 0] = q.x; ss[4 * j + 1] = q.y;
            ss[4 * j + 2] = q.z; ss[4 * j + 3] = q.w;
        }

        int pos[16];
#pragma unroll
        for (int j = 0; j < 16; j++) {
            pos[j] = -1;
            if (dd[j] >= lo && dd[j] < hi) pos[j] = atomicAdd(&deg[dd[j]], 1);
        }
#pragma unroll
        for (int j = 0; j < 16; j++) {
            if (pos[j] >= 0 && pos[j] < MAX_DEG)
                col[(size_t)dd[j] * MAX_DEG + pos[j]] = ss[j];
        }
    }
}

// ---------------- helpers ----------------

__device__ __forceinline__ void fma8(float* acc, uint4 v, float w) {
    const __half2* h = (const __half2*)&v;
#pragma unroll
    for (int j = 0; j < 4; j++) {
        acc[2 * j]     += w * __low2float(h[j]);
        acc[2 * j + 1] += w * __high2float(h[j]);
    }
}

// ---------------- aggregation: PLANE-SPLIT gather (per-XCD L2-resident 3.2MB plane) ----------------
// grid = 2 * 782; plane = blockIdx&1 (round-robin -> XCD parity == plane).
// Per block: 64 nodes x 32 features; quad (4 lanes) per node, t = 16B chunk of 64B row.
// scale_src=1 (layer 1): acc = Σ dinv[s]*T[s] + dv*T[d]; else plain sums.
// mode 0: OUT = dv*gelu(acc*dv + b)*dv ; mode 1: OUT = acc*dv. Normal cached stores (no NT).

__global__ __launch_bounds__(256) void k_agg(const __half* __restrict__ T,
                                             const int* __restrict__ col,
                                             const int* __restrict__ indeg,
                                             const float* __restrict__ b,
                                             __half* __restrict__ OUT,
                                             int mode, int scale_src) {
    int plane = blockIdx.x & 1;
    int base  = (blockIdx.x >> 1) * AGG_NPB;
    int lane = threadIdx.x & 63;
    int wv   = threadIdx.x >> 6;
    int q = lane >> 2, t = lane & 3;     // quad = node, t = 16B chunk of 64B plane-row
    int local = wv * 16 + q;
    int d = base + local;
    if (d >= N_NODES) return;            // tail: whole quads drop, no barriers below

    int dgf = indeg[d];
    int dg = dgf > MAX_DEG ? MAX_DEG : dgf;
    float dv = rsqrtf((float)(dgf + 1));
    const __half* P = T + (size_t)plane * PSTRIDE;

    float acc[8];
#pragma unroll
    for (int j = 0; j < 8; j++) acc[j] = 0.f;
    fma8(acc, *(const uint4*)(P + (size_t)d * 32 + t * 8), scale_src ? dv : 1.0f);

    const int* cl = col + (size_t)d * MAX_DEG;   // 4-lane broadcast reads
    int i = 0;
    for (; i + 4 <= dg; i += 4) {
        int s0 = cl[i], s1 = cl[i + 1], s2 = cl[i + 2], s3 = cl[i + 3];
        uint4 v0 = *(const uint4*)(P + (size_t)s0 * 32 + t * 8);
        uint4 v1 = *(const uint4*)(P + (size_t)s1 * 32 + t * 8);
        uint4 v2 = *(const uint4*)(P + (size_t)s2 * 32 + t * 8);
        uint4 v3 = *(const uint4*)(P + (size_t)s3 * 32 + t * 8);
        float w0 = 1.f, w1 = 1.f, w2 = 1.f, w3 = 1.f;
        if (scale_src) {
            w0 = rsqrtf((float)(indeg[s0] + 1));
            w1 = rsqrtf((float)(indeg[s1] + 1));
            w2 = rsqrtf((float)(indeg[s2] + 1));
            w3 = rsqrtf((float)(indeg[s3] + 1));
        }
        fma8(acc, v0, w0); fma8(acc, v1, w1); fma8(acc, v2, w2); fma8(acc, v3, w3);
    }
    for (; i < dg; i++) {
        int s = cl[i];
        float w = scale_src ? rsqrtf((float)(indeg[s] + 1)) : 1.f;
        fma8(acc, *(const uint4*)(P + (size_t)s * 32 + t * 8), w);
    }

    float o[8];
#pragma unroll
    for (int j = 0; j < 8; j++) o[j] = acc[j] * dv;
    if (mode == 0) {
#pragma unroll
        for (int j = 0; j < 8; j++) {
            float v = o[j] + b[plane * 32 + t * 8 + j];
            float u2 = 0.7978845608028654f * (v + 0.044715f * v * v * v);
            float th = 1.0f - 2.0f / (__expf(2.0f * u2) + 1.0f);
            o[j] = 0.5f * v * (1.0f + th) * dv;   // pre-scale for next layer
        }
    }
    __half2 hh[4];
#pragma unroll
    for (int j = 0; j < 4; j++) hh[j] = __floats2half2_rn(o[2 * j], o[2 * j + 1]);
    *(uint4*)(OUT + (size_t)plane * PSTRIDE + (size_t)d * 32 + t * 8) = *(uint4*)hh;
}

// ---------------- MFMA GEMM layer 2 (plane loads/stores, W2 self-packed) ----------------

__global__ __launch_bounds__(256) void k_mfma2(const __half* __restrict__ A,
                                               const float* __restrict__ W2,
                                               __half* __restrict__ C) {
    constexpr int S = HID / 32;
    __shared__ __half wlds[HID * HID];   // 8 KB
#pragma unroll
    for (int u = 0; u < 4; u++) {
        int o = threadIdx.x * 16 + u * 4;    // 4096 floats / 256 thr
        float4 w = *(const float4*)(W2 + o);
        int k = o >> 6, n = o & 63;
        int bi = (((k >> 3) * 64) + n) * 8 + (k & 7);
        wlds[bi]      = __float2half(w.x);
        wlds[bi + 8]  = __float2half(w.y);
        wlds[bi + 16] = __float2half(w.z);
        wlds[bi + 24] = __float2half(w.w);
    }
    __syncthreads();

    int wv   = threadIdx.x >> 6;
    int lane = threadIdx.x & 63;
    int quad = lane >> 4, l15 = lane & 15;
    int row0 = blockIdx.x * 64 + wv * 16;
    if (row0 >= N_NODES) return;

    half8 bf[S][4];
#pragma unroll
    for (int s = 0; s < S; s++)
#pragma unroll
        for (int j = 0; j < 4; j++)
            bf[s][j] = *(const half8*)&wlds[(((4 * s + quad) * 64) + 16 * j + l15) * 8];

    floatx4 acc[4];
#pragma unroll
    for (int j = 0; j < 4; j++) acc[j] = 0.f;

    int arow = row0 + l15;
#pragma unroll
    for (int s = 0; s < S; s++) {
        half8 af = *(const half8*)(A + (size_t)s * PSTRIDE + (size_t)arow * 32 + quad * 8);
#pragma unroll
        for (int j = 0; j < 4; j++)
            acc[j] = __builtin_amdgcn_mfma_f32_16x16x32_f16(af, bf[s][j], acc[j], 0, 0, 0);
    }
#pragma unroll
    for (int j = 0; j < 4; j++)
#pragma unroll
        for (int r = 0; r < 4; r++)
            C[(size_t)(j >> 1) * PSTRIDE + (size_t)(row0 + quad * 4 + r) * 32 +
              16 * (j & 1) + l15] = __float2half(acc[j][r]);
}

// ---------------- fused segmented mean-pool + final GEMM (batch is SORTED) ----------------

__global__ __launch_bounds__(256) void k_pool_out(const __half* __restrict__ A,
                                                  const int* __restrict__ batch,
                                                  const float* __restrict__ W3,
                                                  const float* __restrict__ b3,
                                                  float* __restrict__ out) {
    int g = blockIdx.x;
    int lo = 0, hi = N_NODES;
    while (lo < hi) { int m = (lo + hi) >> 1; if (batch[m] < g) lo = m + 1; else hi = m; }
    int lo2 = lo, hi2 = N_NODES;
    while (lo2 < hi2) { int m = (lo2 + hi2) >> 1; if (batch[m] < g + 1) lo2 = m + 1; else hi2 = m; }
    int start = lo, end = lo2;

    int lane = threadIdx.x & 63;
    int wave = threadIdx.x >> 6;
    const __half* Ap = A + (size_t)(lane >> 5) * PSTRIDE + (lane & 31);
    float acc = 0.f;
    for (int n = start + wave; n < end; n += 4)
        acc += __half2float(Ap[(size_t)n * 32]);

    __shared__ float part[4][HID];
    __shared__ float pooled[HID];
    part[wave][lane] = acc;
    __syncthreads();
    if (threadIdx.x < HID)
        pooled[threadIdx.x] = part[0][threadIdx.x] + part[1][threadIdx.x] +
                              part[2][threadIdx.x] + part[3][threadIdx.x];
    __syncthreads();

    if (threadIdx.x < OUT_DIM) {
        float cntf = (float)(end - start);
        float inv = 1.0f / fmaxf(cntf, 1.0f);
        float s = 0.f;
#pragma unroll
        for (int k = 0; k < HID; k++) s += pooled[k] * W3[k * OUT_DIM + threadIdx.x];
        out[g * OUT_DIM + threadIdx.x] = (s + cntf * b3[threadIdx.x]) * inv;
    }
}

// ---------------- launch ----------------

extern "C" void kernel_launch(void* const* d_in, const int* in_sizes, int n_in,
                              void* d_out, int out_size, void* d_ws, size_t ws_size,
                              hipStream_t stream) {
    const float* x     = (const float*)d_in[0];
    const int*   ei    = (const int*)d_in[1];
    const int*   batch = (const int*)d_in[2];
    const float* W1    = (const float*)d_in[4];
    const float* b1    = (const float*)d_in[5];
    const float* W2    = (const float*)d_in[6];
    const float* b2    = (const float*)d_in[7];
    const float* W3    = (const float*)d_in[8];
    const float* b3    = (const float*)d_in[9];
    float* out = (float*)d_out;

    const int* esrc = ei;
    const int* edst = ei + N_EDGES;

    // workspace layout
    int*    deg  = (int*)d_ws;                           // 50000 (zeroed; doubles as cursor)
    int*    col  = deg + N_NODES;                        // 3.2M ints (12.8 MB)
    __half* t    = (__half*)(col + (size_t)N_NODES * MAX_DEG);   // 2 planes
    __half* p    = t + 2 * PSTRIDE;                              // 2 planes

    (void)hipMemsetAsync(deg, 0, (size_t)N_NODES * 4, stream);

    const int CHUNKS = (N_EDGES + EPB - 1) / EPB;        // 196
    const int AB = 2 * ((N_NODES + AGG_NPB - 1) / AGG_NPB);   // 2 planes x 782

    // fused layer-1 GEMM (plane store) || edge build
    k_fused1<<<GEMM_BLKS + CHUNKS * PARTS, 256, 0, stream>>>(x, W1, t, esrc, edst, deg, col);
    // layer 1 aggregate (dinv weights) + gelu + prescale:  p = dv.*gelu(conv1)
    k_agg<<<AB, 256, 0, stream>>>(t, col, deg, b1, p, 0, 1);
    // layer 2 GEMM: t = p @ W2
    k_mfma2<<<GEMM_BLKS, 256, 0, stream>>>(p, W2, t);
    // layer 2 aggregate
    k_agg<<<AB, 256, 0, stream>>>(t, col, deg, b2, p, 0, 0);
    // layer 3 aggregate (width 64, pre-GEMM)
    k_agg<<<AB, 256, 0, stream>>>(p, col, deg, b3, t, 1, 0);
    // fused mean-pool + 64->128 GEMM
    k_pool_out<<<N_GRAPHS, 256, 0, stream>>>(t, batch, W3, b3, out);
}

// Round 11
// 215.752 us; speedup vs baseline: 1.0764x; 1.0764x over previous
//
#include <hip/hip_runtime.h>
#include <hip/hip_fp16.h>
#include <math.h>

#define N_NODES   50000
#define N_EDGES   800000
#define IN_DIM    128
#define HID       64
#define OUT_DIM   128
#define N_GRAPHS  256
#define MAX_DEG   64      // ELL row stride; P(indeg>64) for Binomial(800k,1/50k) ~ 0
#define PARTS     8       // XCD count; blockIdx%8 -> XCD round-robin heuristic
#define PSIZE     (N_NODES / PARTS)
#define EPB       4096    // edges per build chunk (= 256 threads x 16 edges)
#define AGG_NPB   32      // nodes per agg block (4 waves x 8 octets)
#define DEGP      32      // padded counter stride (ints): 1 counter per 128B line

typedef _Float16 half8 __attribute__((ext_vector_type(8)));
typedef float floatx4 __attribute__((ext_vector_type(4)));

// ---------------- preprocessing ----------------

// XCD-partitioned histogram + ELL fill (padded counters, batched MLP form)
__global__ __launch_bounds__(256) void k_build(const int* __restrict__ src,
                                               const int* __restrict__ dst,
                                               int* __restrict__ deg, int* __restrict__ col) {
    int p     = blockIdx.x & (PARTS - 1);
    int chunk = blockIdx.x >> 3;
    int e0    = chunk * EPB + threadIdx.x * 16;
    if (e0 + 16 > N_EDGES) return;        // tail chunk is 1280 = 80*16 edges: clean cut
    int lo = p * PSIZE, hi = lo + PSIZE;

    int dd[16], ss[16];
    const int4* d4 = (const int4*)(dst + e0);
    const int4* s4 = (const int4*)(src + e0);
#pragma unroll
    for (int j = 0; j < 4; j++) {
        int4 q = d4[j];
        dd[4 * j + 0] = q.x; dd[4 * j + 1] = q.y;
        dd[4 * j + 2] = q.z; dd[4 * j + 3] = q.w;
    }
#pragma unroll
    for (int j = 0; j < 4; j++) {
        int4 q = s4[j];
        ss[4 * j + 0] = q.x; ss[4 * j + 1] = q.y;
        ss[4 * j + 2] = q.z; ss[4 * j + 3] = q.w;
    }

    int pos[16];
#pragma unroll
    for (int j = 0; j < 16; j++) {
        pos[j] = -1;
        if (dd[j] >= lo && dd[j] < hi) pos[j] = atomicAdd(&deg[(size_t)dd[j] * DEGP], 1);
    }
#pragma unroll
    for (int j = 0; j < 16; j++) {
        if (pos[j] >= 0 && pos[j] < MAX_DEG)
            col[(size_t)dd[j] * MAX_DEG + pos[j]] = ss[j];
    }
}

// merged: dinv + compact deg (blocks 0..195) + pack W1 (196..199) + pack W2 (200..201)
__global__ __launch_bounds__(256) void k_prep(const int* __restrict__ deg,
                                              int* __restrict__ degc,
                                              float* __restrict__ dinv,
                                              const float* __restrict__ W1, __half* __restrict__ Wt1,
                                              const float* __restrict__ W2, __half* __restrict__ Wt2) {
    int blk = blockIdx.x;
    if (blk < 196) {
        int n = blk * 256 + threadIdx.x;
        if (n < N_NODES) {
            int dg = deg[(size_t)n * DEGP];
            degc[n] = dg;
            dinv[n] = rsqrtf((float)(dg + 1));  // +1 self-loop
        }
    } else if (blk < 200) {
        int idx = (blk - 196) * 256 + threadIdx.x;   // 0..1023 = (128/8)*64
        int g = idx >> 6, n = idx & 63;
#pragma unroll
        for (int i = 0; i < 8; i++)
            Wt1[idx * 8 + i] = __float2half(W1[(8 * g + i) * 64 + n]);
    } else {
        int idx = (blk - 200) * 256 + threadIdx.x;   // 0..511 = (64/8)*64
        if (idx < 512) {
            int g = idx >> 6, n = idx & 63;
#pragma unroll
            for (int i = 0; i < 8; i++)
                Wt2[idx * 8 + i] = __float2half(W2[(8 * g + i) * 64 + n]);
        }
    }
}

// ---------------- MFMA GEMM layer 1: C = (dinv ⊙ x_fp32) @ W1, cvt fused ----------------

__global__ __launch_bounds__(256) void k_mfma1(const float* __restrict__ A,
                                               const float* __restrict__ dinv,
                                               const __half* __restrict__ Bp,
                                               __half* __restrict__ C) {
    constexpr int K = IN_DIM, S = K / 32;
    int wv   = threadIdx.x >> 6;
    int lane = threadIdx.x & 63;
    int quad = lane >> 4, l15 = lane & 15;
    int row0 = blockIdx.x * 64 + wv * 16;
    if (row0 >= N_NODES) return;   // 50000 % 16 == 0

    half8 bf[S][4];
#pragma unroll
    for (int s = 0; s < S; s++)
#pragma unroll
        for (int j = 0; j < 4; j++)
            bf[s][j] = *(const half8*)(Bp + ((size_t)((4 * s + quad) * 64 + 16 * j + l15)) * 8);

    floatx4 acc[4];
#pragma unroll
    for (int j = 0; j < 4; j++) acc[j] = 0.f;

    int arow = row0 + l15;
    float dv = dinv[arow];
#pragma unroll
    for (int s = 0; s < S; s++) {
        float4 xa = *(const float4*)(A + (size_t)arow * K + 32 * s + quad * 8);
        float4 xb = *(const float4*)(A + (size_t)arow * K + 32 * s + quad * 8 + 4);
        half8 af;
        af[0] = (_Float16)(xa.x * dv); af[1] = (_Float16)(xa.y * dv);
        af[2] = (_Float16)(xa.z * dv); af[3] = (_Float16)(xa.w * dv);
        af[4] = (_Float16)(xb.x * dv); af[5] = (_Float16)(xb.y * dv);
        af[6] = (_Float16)(xb.z * dv); af[7] = (_Float16)(xb.w * dv);
#pragma unroll
        for (int j = 0; j < 4; j++)
            acc[j] = __builtin_amdgcn_mfma_f32_16x16x32_f16(af, bf[s][j], acc[j], 0, 0, 0);
    }
#pragma unroll
    for (int j = 0; j < 4; j++)
#pragma unroll
        for (int r = 0; r < 4; r++)
            C[(size_t)(row0 + quad * 4 + r) * 64 + 16 * j + l15] = __float2half(acc[j][r]);
}

// ---------------- MFMA GEMM layer 2: fp16 A ----------------

__global__ __launch_bounds__(256) void k_mfma2(const __half* __restrict__ A,
                                               const __half* __restrict__ Bp,
                                               __half* __restrict__ C) {
    constexpr int K = HID, S = K / 32;
    int wv   = threadIdx.x >> 6;
    int lane = threadIdx.x & 63;
    int quad = lane >> 4, l15 = lane & 15;
    int row0 = blockIdx.x * 64 + wv * 16;
    if (row0 >= N_NODES) return;

    half8 bf[S][4];
#pragma unroll
    for (int s = 0; s < S; s++)
#pragma unroll
        for (int j = 0; j < 4; j++)
            bf[s][j] = *(const half8*)(Bp + ((size_t)((4 * s + quad) * 64 + 16 * j + l15)) * 8);

    floatx4 acc[4];
#pragma unroll
    for (int j = 0; j < 4; j++) acc[j] = 0.f;

    int arow = row0 + l15;
#pragma unroll
    for (int s = 0; s < S; s++) {
        half8 af = *(const half8*)(A + (size_t)arow * K + 32 * s + quad * 8);
#pragma unroll
        for (int j = 0; j < 4; j++)
            acc[j] = __builtin_amdgcn_mfma_f32_16x16x32_f16(af, bf[s][j], acc[j], 0, 0, 0);
    }
#pragma unroll
    for (int j = 0; j < 4; j++)
#pragma unroll
        for (int r = 0; r < 4; r++)
            C[(size_t)(row0 + quad * 4 + r) * 64 + 16 * j + l15] = __float2half(acc[j][r]);
}

// ---------------- aggregation (R5 structure + deg-limited staging; expf gelu) ----------------
// mode 0: OUT = dinv * gelu_tanh( dinv*(Σ_in T[s] + T[d]) + b )   (pre-scaled for next layer)
// mode 1: OUT = dinv * (Σ_in T[s] + T[d])

__device__ __forceinline__ void add8(float* acc, uint4 v) {
    const __half2* h = (const __half2*)&v;
#pragma unroll
    for (int j = 0; j < 4; j++) {
        acc[2 * j]     += __low2float(h[j]);
        acc[2 * j + 1] += __high2float(h[j]);
    }
}

__global__ __launch_bounds__(256) void k_agg(const __half* __restrict__ T,
                                             const int* __restrict__ col,
                                             const int* __restrict__ indeg,
                                             const float* __restrict__ dinv,
                                             const float* __restrict__ b,
                                             __half* __restrict__ OUT, int mode) {
    __shared__ int cols[AGG_NPB][MAX_DEG + 1];   // +1 pad: octets land in distinct banks
    __shared__ int sdeg[AGG_NPB];
    int base = blockIdx.x * AGG_NPB;

    if (threadIdx.x < AGG_NPB) {
        int g = base + threadIdx.x;
        int dg0 = (g < N_NODES) ? indeg[g] : 0;
        sdeg[threadIdx.x] = dg0 > MAX_DEG ? MAX_DEG : dg0;
    }
    __syncthreads();

    // stage only live ELL slots (mean deg ~16 of 64 -> ~75% fewer col reads)
    for (int idx = threadIdx.x; idx < AGG_NPB * MAX_DEG; idx += 256) {
        int r = idx >> 6, j = idx & 63;
        if (j < sdeg[r]) cols[r][j] = col[(size_t)(base + r) * MAX_DEG + j];
    }
    __syncthreads();

    int lane = threadIdx.x & 63;
    int wv   = threadIdx.x >> 6;
    int q = lane >> 3, t = lane & 7;     // octet = node, t = 16-byte chunk
    int local = wv * 8 + q;
    int d = base + local;
    if (d >= N_NODES) return;            // tail block: whole octets drop out

    int dg = sdeg[local];

    float acc[8];
#pragma unroll
    for (int j = 0; j < 8; j++) acc[j] = 0.f;
    add8(acc, *(const uint4*)(T + (size_t)d * HID + t * 8));   // self term

    const int* cl = cols[local];
    int i = 0;
    for (; i + 4 <= dg; i += 4) {
        int s0 = cl[i], s1 = cl[i + 1], s2 = cl[i + 2], s3 = cl[i + 3];
        uint4 v0 = *(const uint4*)(T + (size_t)s0 * HID + t * 8);
        uint4 v1 = *(const uint4*)(T + (size_t)s1 * HID + t * 8);
        uint4 v2 = *(const uint4*)(T + (size_t)s2 * HID + t * 8);
        uint4 v3 = *(const uint4*)(T + (size_t)s3 * HID + t * 8);
        add8(acc, v0); add8(acc, v1); add8(acc, v2); add8(acc, v3);
    }
    for (; i < dg; i++) {
        int s = cl[i];
        add8(acc, *(const uint4*)(T + (size_t)s * HID + t * 8));
    }

    float dv = dinv[d];
    float o[8];
#pragma unroll
    for (int j = 0; j < 8; j++) o[j] = acc[j] * dv;
    if (mode == 0) {
#pragma unroll
        for (int j = 0; j < 8; j++) {
            float v = o[j] + b[t * 8 + j];
            float u2 = 0.7978845608028654f * (v + 0.044715f * v * v * v);
            // tanh(u) = 1 - 2/(exp(2u)+1)  (v_exp_f32 path, no libm tanhf)
            float th = 1.0f - 2.0f / (__expf(2.0f * u2) + 1.0f);
            o[j] = 0.5f * v * (1.0f + th) * dv;   // pre-scale for next layer
        }
    }
    __half2 hh[4];
#pragma unroll
    for (int j = 0; j < 4; j++) hh[j] = __floats2half2_rn(o[2 * j], o[2 * j + 1]);
    *(uint4*)(OUT + (size_t)d * HID + t * 8) = *(uint4*)hh;
}

// ---------------- fused segmented mean-pool + final GEMM (batch is SORTED) ----------------

__global__ __launch_bounds__(256) void k_pool_out(const __half* __restrict__ A,
                                                  const int* __restrict__ batch,
                                                  const float* __restrict__ W3,
                                                  const float* __restrict__ b3,
                                                  float* __restrict__ out) {
    int g = blockIdx.x;
    int lo = 0, hi = N_NODES;
    while (lo < hi) { int m = (lo + hi) >> 1; if (batch[m] < g) lo = m + 1; else hi = m; }
    int lo2 = lo, hi2 = N_NODES;
    while (lo2 < hi2) { int m = (lo2 + hi2) >> 1; if (batch[m] < g + 1) lo2 = m + 1; else hi2 = m; }
    int start = lo, end = lo2;

    int lane = threadIdx.x & 63;
    int wave = threadIdx.x >> 6;
    float acc = 0.f;
    for (int n = start + wave; n < end; n += 4)
        acc += __half2float(A[(size_t)n * HID + lane]);

    __shared__ float part[4][HID];
    __shared__ float pooled[HID];
    part[wave][lane] = acc;
    __syncthreads();
    if (threadIdx.x < HID)
        pooled[threadIdx.x] = part[0][threadIdx.x] + part[1][threadIdx.x] +
                              part[2][threadIdx.x] + part[3][threadIdx.x];
    __syncthreads();

    if (threadIdx.x < OUT_DIM) {
        float cntf = (float)(end - start);
        float inv = 1.0f / fmaxf(cntf, 1.0f);
        float s = 0.f;
#pragma unroll
        for (int k = 0; k < HID; k++) s += pooled[k] * W3[k * OUT_DIM + threadIdx.x];
        out[g * OUT_DIM + threadIdx.x] = (s + cntf * b3[threadIdx.x]) * inv;
    }
}

// ---------------- launch ----------------

extern "C" void kernel_launch(void* const* d_in, const int* in_sizes, int n_in,
                              void* d_out, int out_size, void* d_ws, size_t ws_size,
                              hipStream_t stream) {
    const float* x     = (const float*)d_in[0];
    const int*   ei    = (const int*)d_in[1];
    const int*   batch = (const int*)d_in[2];
    const float* W1    = (const float*)d_in[4];
    const float* b1    = (const float*)d_in[5];
    const float* W2    = (const float*)d_in[6];
    const float* b2    = (const float*)d_in[7];
    const float* W3    = (const float*)d_in[8];
    const float* b3    = (const float*)d_in[9];
    float* out = (float*)d_out;

    const int* esrc = ei;
    const int* edst = ei + N_EDGES;

    // workspace layout
    int*    deg  = (int*)d_ws;                           // 50000 x DEGP (padded; zeroed)
    int*    degc = deg + (size_t)N_NODES * DEGP;         // 50000 compact
    float*  dinv = (float*)(degc + N_NODES);             // 50000
    int*    col  = (int*)(dinv + N_NODES);               // 3.2M ints (12.8 MB)
    __half* t    = (__half*)(col + (size_t)N_NODES * MAX_DEG);   // 3.2M halves
    __half* p    = t + (size_t)N_NODES * HID;                    // 3.2M halves
    __half* Wt1  = p + (size_t)N_NODES * HID;                    // 8192 halves
    __half* Wt2  = Wt1 + IN_DIM * HID;                           // 4096 halves

    (void)hipMemsetAsync(deg, 0, (size_t)N_NODES * DEGP * 4, stream);

    const int CHUNKS = (N_EDGES + EPB - 1) / EPB;        // 196
    k_build<<<CHUNKS * PARTS, 256, 0, stream>>>(esrc, edst, deg, col);
    k_prep<<<202, 256, 0, stream>>>(deg, degc, dinv, W1, Wt1, W2, Wt2);

    const int GB = (N_NODES + 63) / 64;        // 782 MFMA blocks
    const int AB = (N_NODES + AGG_NPB - 1) / AGG_NPB;   // 1563 agg blocks

    // layer 1 (x-cvt + dinv pre-scale fused into MFMA A-load)
    k_mfma1<<<GB, 256, 0, stream>>>(x, dinv, Wt1, t);
    k_agg<<<AB, 256, 0, stream>>>(t, col, degc, dinv, b1, p, 0);
    // layer 2
    k_mfma2<<<GB, 256, 0, stream>>>(p, Wt2, t);
    k_agg<<<AB, 256, 0, stream>>>(t, col, degc, dinv, b2, p, 0);
    // layer 3 aggregate (width 64, pre-GEMM)
    k_agg<<<AB, 256, 0, stream>>>(p, col, degc, dinv, b3, t, 1);
    // fused mean-pool + 64->128 GEMM
    k_pool_out<<<N_GRAPHS, 256, 0, stream>>>(t, batch, W3, b3, out);
}

// Round 12
// 214.840 us; speedup vs baseline: 1.0810x; 1.0042x over previous
//
#include <hip/hip_runtime.h>
#include <hip/hip_fp16.h>
#include <math.h>

#define N_NODES   50000
#define N_EDGES   800000
#define IN_DIM    128
#define HID       64
#define OUT_DIM   128
#define N_GRAPHS  256
#define MAX_DEG   64      // ELL row stride; P(indeg>64) for Binomial(800k,1/50k) ~ 0
#define PARTS     8       // XCD count; blockIdx%8 -> XCD round-robin heuristic
#define PSIZE     (N_NODES / PARTS)
#define EPB       4096    // edges per build chunk (= 256 threads x 16 edges)
#define AGG_NPB   32      // nodes per agg block (4 waves x 8 octets)
#define DEGP      32      // padded counter stride (ints): 1 counter per 128B line
#define GEMM_BLKS 782     // ceil(50000/64)

typedef _Float16 half8 __attribute__((ext_vector_type(8)));
typedef float floatx4 __attribute__((ext_vector_type(4)));

// ---------------- fused: layer-1 GEMM (UNSCALED x@W1, W1 self-packed to LDS) || edge build ----------------
// GEMM has no dependency on the edge histogram -> the atomic-latency-bound build
// and the MFMA/HBM-bound GEMM overlap on-chip (verified R7/R9: fused1 ~= build alone).

__global__ __launch_bounds__(256) void k_fused1(const float* __restrict__ A,
                                                const float* __restrict__ W1,
                                                __half* __restrict__ C,
                                                const int* __restrict__ src,
                                                const int* __restrict__ dst,
                                                int* __restrict__ deg,
                                                int* __restrict__ col) {
    if (blockIdx.x < GEMM_BLKS) {
        constexpr int K = IN_DIM, S = K / 32;
        __shared__ __half wlds[IN_DIM * HID];   // packed B fragments, 16 KB

        // self-pack: coalesced fp32 read of W1 (L2-resident), packed fp16 to LDS
#pragma unroll
        for (int u = 0; u < 8; u++) {
            int o = threadIdx.x * 32 + u * 4;          // 8192 floats / 256 thr
            float4 w = *(const float4*)(W1 + o);
            int k = o >> 6, n = o & 63;
            int bi = (((k >> 3) * 64) + n) * 8 + (k & 7);
            wlds[bi]      = __float2half(w.x);
            wlds[bi + 8]  = __float2half(w.y);
            wlds[bi + 16] = __float2half(w.z);
            wlds[bi + 24] = __float2half(w.w);
        }
        __syncthreads();

        int wv   = threadIdx.x >> 6;
        int lane = threadIdx.x & 63;
        int quad = lane >> 4, l15 = lane & 15;
        int row0 = blockIdx.x * 64 + wv * 16;
        if (row0 >= N_NODES) return;   // after barrier: tail waves drop out

        half8 bf[S][4];
#pragma unroll
        for (int s = 0; s < S; s++)
#pragma unroll
            for (int j = 0; j < 4; j++)
                bf[s][j] = *(const half8*)&wlds[(((4 * s + quad) * 64) + 16 * j + l15) * 8];

        floatx4 acc[4];
#pragma unroll
        for (int j = 0; j < 4; j++) acc[j] = 0.f;

        int arow = row0 + l15;
#pragma unroll
        for (int s = 0; s < S; s++) {
            float4 xa = *(const float4*)(A + (size_t)arow * K + 32 * s + quad * 8);
            float4 xb = *(const float4*)(A + (size_t)arow * K + 32 * s + quad * 8 + 4);
            half8 af;
            af[0] = (_Float16)xa.x; af[1] = (_Float16)xa.y;
            af[2] = (_Float16)xa.z; af[3] = (_Float16)xa.w;
            af[4] = (_Float16)xb.x; af[5] = (_Float16)xb.y;
            af[6] = (_Float16)xb.z; af[7] = (_Float16)xb.w;
#pragma unroll
            for (int j = 0; j < 4; j++)
                acc[j] = __builtin_amdgcn_mfma_f32_16x16x32_f16(af, bf[s][j], acc[j], 0, 0, 0);
        }
#pragma unroll
        for (int j = 0; j < 4; j++)
#pragma unroll
            for (int r = 0; r < 4; r++)
                C[(size_t)(row0 + quad * 4 + r) * 64 + 16 * j + l15] = __float2half(acc[j][r]);
    } else {
        int bid   = blockIdx.x - GEMM_BLKS;
        int p     = bid & (PARTS - 1);
        int chunk = bid >> 3;
        int e0    = chunk * EPB + threadIdx.x * 16;
        if (e0 + 16 > N_EDGES) return;        // tail chunk is 1280 = 80*16 edges: clean cut
        int lo = p * PSIZE, hi = lo + PSIZE;

        int dd[16], ss[16];
        const int4* d4 = (const int4*)(dst + e0);
        const int4* s4 = (const int4*)(src + e0);
#pragma unroll
        for (int j = 0; j < 4; j++) {
            int4 q = d4[j];
            dd[4 * j + 0] = q.x; dd[4 * j + 1] = q.y;
            dd[4 * j + 2] = q.z; dd[4 * j + 3] = q.w;
        }
#pragma unroll
        for (int j = 0; j < 4; j++) {
            int4 q = s4[j];
            ss[4 * j + 0] = q.x; ss[4 * j + 1] = q.y;
            ss[4 * j + 2] = q.z; ss[4 * j + 3] = q.w;
        }

        int pos[16];
#pragma unroll
        for (int j = 0; j < 16; j++) {
            pos[j] = -1;
            if (dd[j] >= lo && dd[j] < hi) pos[j] = atomicAdd(&deg[(size_t)dd[j] * DEGP], 1);
        }
#pragma unroll
        for (int j = 0; j < 16; j++) {
            if (pos[j] >= 0 && pos[j] < MAX_DEG)
                col[(size_t)dd[j] * MAX_DEG + pos[j]] = ss[j];
        }
    }
}

// ---------------- scale pass: degc/dinv compute + t *= dinv (row-wise) + W2 pack ----------------
// Replaces mfma1's fused pre-scale (now overlapped away) at streaming cost: 12.8 MB ~ 3 us.

__global__ __launch_bounds__(256) void k_scale(const int* __restrict__ deg,
                                               int* __restrict__ degc,
                                               float* __restrict__ dinv,
                                               __half* __restrict__ t,
                                               const float* __restrict__ W2,
                                               __half* __restrict__ Wt2) {
    int blk = blockIdx.x;
    if (blk < 196) {
        __shared__ float sdv[256];
        int n0 = blk * 256;
        int n = n0 + threadIdx.x;
        float dv = 1.f;
        if (n < N_NODES) {
            int dg = deg[(size_t)n * DEGP];
            degc[n] = dg;
            dv = rsqrtf((float)(dg + 1));  // +1 self-loop
            dinv[n] = dv;
        }
        sdv[threadIdx.x] = dv;
        __syncthreads();
        // scale 256 rows x 64 halves: 2048 uint4 chunks, coalesced (8 thr / 128B row)
#pragma unroll
        for (int it = 0; it < 8; it++) {
            int idx = it * 256 + threadIdx.x;
            int r = idx >> 3, c = idx & 7;
            int node = n0 + r;
            if (node < N_NODES) {
                uint4 v = *(const uint4*)(t + (size_t)node * HID + c * 8);
                float w = sdv[r];
                __half2* h = (__half2*)&v;
#pragma unroll
                for (int j = 0; j < 4; j++)
                    h[j] = __floats2half2_rn(__low2float(h[j]) * w, __high2float(h[j]) * w);
                *(uint4*)(t + (size_t)node * HID + c * 8) = v;
            }
        }
    } else {
        int idx = (blk - 196) * 256 + threadIdx.x;   // 0..511 = (64/8)*64
        if (idx < 512) {
            int g = idx >> 6, n = idx & 63;
#pragma unroll
            for (int i = 0; i < 8; i++)
                Wt2[idx * 8 + i] = __float2half(W2[(8 * g + i) * 64 + n]);
        }
    }
}

// ---------------- MFMA GEMM layer 2: fp16 A ----------------

__global__ __launch_bounds__(256) void k_mfma2(const __half* __restrict__ A,
                                               const __half* __restrict__ Bp,
                                               __half* __restrict__ C) {
    constexpr int K = HID, S = K / 32;
    int wv   = threadIdx.x >> 6;
    int lane = threadIdx.x & 63;
    int quad = lane >> 4, l15 = lane & 15;
    int row0 = blockIdx.x * 64 + wv * 16;
    if (row0 >= N_NODES) return;

    half8 bf[S][4];
#pragma unroll
    for (int s = 0; s < S; s++)
#pragma unroll
        for (int j = 0; j < 4; j++)
            bf[s][j] = *(const half8*)(Bp + ((size_t)((4 * s + quad) * 64 + 16 * j + l15)) * 8);

    floatx4 acc[4];
#pragma unroll
    for (int j = 0; j < 4; j++) acc[j] = 0.f;

    int arow = row0 + l15;
#pragma unroll
    for (int s = 0; s < S; s++) {
        half8 af = *(const half8*)(A + (size_t)arow * K + 32 * s + quad * 8);
#pragma unroll
        for (int j = 0; j < 4; j++)
            acc[j] = __builtin_amdgcn_mfma_f32_16x16x32_f16(af, bf[s][j], acc[j], 0, 0, 0);
    }
#pragma unroll
    for (int j = 0; j < 4; j++)
#pragma unroll
        for (int r = 0; r < 4; r++)
            C[(size_t)(row0 + quad * 4 + r) * 64 + 16 * j + l15] = __float2half(acc[j][r]);
}

// ---------------- aggregation (R11 verbatim: LDS-staged, deg-limited, expf gelu) ----------------
// mode 0: OUT = dinv * gelu_tanh( dinv*(Σ_in T[s] + T[d]) + b )   (pre-scaled for next layer)
// mode 1: OUT = dinv * (Σ_in T[s] + T[d])

__device__ __forceinline__ void add8(float* acc, uint4 v) {
    const __half2* h = (const __half2*)&v;
#pragma unroll
    for (int j = 0; j < 4; j++) {
        acc[2 * j]     += __low2float(h[j]);
        acc[2 * j + 1] += __high2float(h[j]);
    }
}

__global__ __launch_bounds__(256) void k_agg(const __half* __restrict__ T,
                                             const int* __restrict__ col,
                                             const int* __restrict__ indeg,
                                             const float* __restrict__ dinv,
                                             const float* __restrict__ b,
                                             __half* __restrict__ OUT, int mode) {
    __shared__ int cols[AGG_NPB][MAX_DEG + 1];   // +1 pad: octets land in distinct banks
    __shared__ int sdeg[AGG_NPB];
    int base = blockIdx.x * AGG_NPB;

    if (threadIdx.x < AGG_NPB) {
        int g = base + threadIdx.x;
        int dg0 = (g < N_NODES) ? indeg[g] : 0;
        sdeg[threadIdx.x] = dg0 > MAX_DEG ? MAX_DEG : dg0;
    }
    __syncthreads();

    // stage only live ELL slots (mean deg ~16 of 64 -> ~75% fewer col reads)
    for (int idx = threadIdx.x; idx < AGG_NPB * MAX_DEG; idx += 256) {
        int r = idx >> 6, j = idx & 63;
        if (j < sdeg[r]) cols[r][j] = col[(size_t)(base + r) * MAX_DEG + j];
    }
    __syncthreads();

    int lane = threadIdx.x & 63;
    int wv   = threadIdx.x >> 6;
    int q = lane >> 3, t = lane & 7;     // octet = node, t = 16-byte chunk
    int local = wv * 8 + q;
    int d = base + local;
    if (d >= N_NODES) return;            // tail block: whole octets drop out

    int dg = sdeg[local];

    float acc[8];
#pragma unroll
    for (int j = 0; j < 8; j++) acc[j] = 0.f;
    add8(acc, *(const uint4*)(T + (size_t)d * HID + t * 8));   // self term

    const int* cl = cols[local];
    int i = 0;
    for (; i + 4 <= dg; i += 4) {
        int s0 = cl[i], s1 = cl[i + 1], s2 = cl[i + 2], s3 = cl[i + 3];
        uint4 v0 = *(const uint4*)(T + (size_t)s0 * HID + t * 8);
        uint4 v1 = *(const uint4*)(T + (size_t)s1 * HID + t * 8);
        uint4 v2 = *(const uint4*)(T + (size_t)s2 * HID + t * 8);
        uint4 v3 = *(const uint4*)(T + (size_t)s3 * HID + t * 8);
        add8(acc, v0); add8(acc, v1); add8(acc, v2); add8(acc, v3);
    }
    for (; i < dg; i++) {
        int s = cl[i];
        add8(acc, *(const uint4*)(T + (size_t)s * HID + t * 8));
    }

    float dv = dinv[d];
    float o[8];
#pragma unroll
    for (int j = 0; j < 8; j++) o[j] = acc[j] * dv;
    if (mode == 0) {
#pragma unroll
        for (int j = 0; j < 8; j++) {
            float v = o[j] + b[t * 8 + j];
            float u2 = 0.7978845608028654f * (v + 0.044715f * v * v * v);
            float th = 1.0f - 2.0f / (__expf(2.0f * u2) + 1.0f);
            o[j] = 0.5f * v * (1.0f + th) * dv;   // pre-scale for next layer
        }
    }
    __half2 hh[4];
#pragma unroll
    for (int j = 0; j < 4; j++) hh[j] = __floats2half2_rn(o[2 * j], o[2 * j + 1]);
    *(uint4*)(OUT + (size_t)d * HID + t * 8) = *(uint4*)hh;
}

// ---------------- fused segmented mean-pool + final GEMM (batch is SORTED) ----------------

__global__ __launch_bounds__(256) void k_pool_out(const __half* __restrict__ A,
                                                  const int* __restrict__ batch,
                                                  const float* __restrict__ W3,
                                                  const float* __restrict__ b3,
                                                  float* __restrict__ out) {
    int g = blockIdx.x;
    int lo = 0, hi = N_NODES;
    while (lo < hi) { int m = (lo + hi) >> 1; if (batch[m] < g) lo = m + 1; else hi = m; }
    int lo2 = lo, hi2 = N_NODES;
    while (lo2 < hi2) { int m = (lo2 + hi2) >> 1; if (batch[m] < g + 1) lo2 = m + 1; else hi2 = m; }
    int start = lo, end = lo2;

    int lane = threadIdx.x & 63;
    int wave = threadIdx.x >> 6;
    float acc = 0.f;
    for (int n = start + wave; n < end; n += 4)
        acc += __half2float(A[(size_t)n * HID + lane]);

    __shared__ float part[4][HID];
    __shared__ float pooled[HID];
    part[wave][lane] = acc;
    __syncthreads();
    if (threadIdx.x < HID)
        pooled[threadIdx.x] = part[0][threadIdx.x] + part[1][threadIdx.x] +
                              part[2][threadIdx.x] + part[3][threadIdx.x];
    __syncthreads();

    if (threadIdx.x < OUT_DIM) {
        float cntf = (float)(end - start);
        float inv = 1.0f / fmaxf(cntf, 1.0f);
        float s = 0.f;
#pragma unroll
        for (int k = 0; k < HID; k++) s += pooled[k] * W3[k * OUT_DIM + threadIdx.x];
        out[g * OUT_DIM + threadIdx.x] = (s + cntf * b3[threadIdx.x]) * inv;
    }
}

// ---------------- launch ----------------

extern "C" void kernel_launch(void* const* d_in, const int* in_sizes, int n_in,
                              void* d_out, int out_size, void* d_ws, size_t ws_size,
                              hipStream_t stream) {
    const float* x     = (const float*)d_in[0];
    const int*   ei    = (const int*)d_in[1];
    const int*   batch = (const int*)d_in[2];
    const float* W1    = (const float*)d_in[4];
    const float* b1    = (const float*)d_in[5];
    const float* W2    = (const float*)d_in[6];
    const float* b2    = (const float*)d_in[7];
    const float* W3    = (const float*)d_in[8];
    const float* b3    = (const float*)d_in[9];
    float* out = (float*)d_out;

    const int* esrc = ei;
    const int* edst = ei + N_EDGES;

    // workspace layout
    int*    deg  = (int*)d_ws;                           // 50000 x DEGP (padded; zeroed)
    int*    degc = deg + (size_t)N_NODES * DEGP;         // 50000 compact
    float*  dinv = (float*)(degc + N_NODES);             // 50000
    int*    col  = (int*)(dinv + N_NODES);               // 3.2M ints (12.8 MB)
    __half* t    = (__half*)(col + (size_t)N_NODES * MAX_DEG);   // 3.2M halves
    __half* p    = t + (size_t)N_NODES * HID;                    // 3.2M halves
    __half* Wt2  = p + (size_t)N_NODES * HID;                    // 4096 halves

    (void)hipMemsetAsync(deg, 0, (size_t)N_NODES * DEGP * 4, stream);

    const int CHUNKS = (N_EDGES + EPB - 1) / EPB;        // 196
    const int AB = (N_NODES + AGG_NPB - 1) / AGG_NPB;    // 1563 agg blocks

    // fused layer-1 GEMM (unscaled, W1 self-packed) || edge build
    k_fused1<<<GEMM_BLKS + CHUNKS * PARTS, 256, 0, stream>>>(x, W1, t, esrc, edst, deg, col);
    // dinv/degc + t *= dinv + W2 pack  (restores R11's pre-scaled-t contract at ~3 us)
    k_scale<<<198, 256, 0, stream>>>(deg, degc, dinv, t, W2, Wt2);

    // layer 1 aggregate (pre-scaled input, plain sums)
    k_agg<<<AB, 256, 0, stream>>>(t, col, degc, dinv, b1, p, 0);
    // layer 2 GEMM
    k_mfma2<<<GEMM_BLKS, 256, 0, stream>>>(p, Wt2, t);
    k_agg<<<AB, 256, 0, stream>>>(t, col, degc, dinv, b2, p, 0);
    // layer 3 aggregate (width 64, pre-GEMM)
    k_agg<<<AB, 256, 0, stream>>>(p, col, degc, dinv, b3, t, 1);
    // fused mean-pool + 64->128 GEMM
    k_pool_out<<<N_GRAPHS, 256, 0, stream>>>(t, batch, W3, b3, out);
}